// Round 1
// baseline (108.896 us; speedup 1.0000x reference)
//
#include <hip/hip_runtime.h>

// Problem constants (fixed by the reference's setup_inputs):
//   B=128 batches, S=32768 sequence, P=65536 path steps.
#define NB 128
#define NS 32768
#define NP 65536
#define POS_W 5.0f

constexpr int MASK_WORDS = (NB * NS) / 32;   // 131072 words = 512 KB bitmask
constexpr int LOSS_BLOCKS = 1024;

// ws layout:
//   [0, MASK_WORDS*4)                     : gt bitmask (zeroed each launch)
//   [MASK_WORDS*4, +4)                    : int32 layout-detect flag
//   [MASK_WORDS*4 + 16, +LOSS_BLOCKS*4)   : per-block partial sums

// ---------------------------------------------------------------------------
// Detect whether paths buffer is int32 (JAX x64 off) or int64 layout.
// Word at odd index 2P-1: int32 layout -> pj[b=0,k=P-1] (max of 65536 draws
// from [0,32768), certainly nonzero); int64 layout -> hi word of an int64 = 0.
__global__ void detect_kernel(const int* __restrict__ pw, int* __restrict__ flag) {
    if (threadIdx.x == 0 && blockIdx.x == 0) {
        flag[0] = (pw[2 * (size_t)NP - 1] != 0) ? 0 : 1;  // 0 = int32 (shift 0), 1 = int64 (shift 1)
    }
}

// ---------------------------------------------------------------------------
// One thread per (b, k). is_first via sorted-run boundary (pj sorted per batch).
__global__ __launch_bounds__(256)
void gt_kernel(const int* __restrict__ pw, const int* __restrict__ targets,
               unsigned int* __restrict__ mask, const int* __restrict__ flag) {
    const int shift = flag[0];                 // uniform across all threads
    const int b = blockIdx.y;
    const int k = blockIdx.x * blockDim.x + threadIdx.x;   // k in [0, NP)
    const size_t e = ((size_t)b * NP + (size_t)k) * 2;     // flat element index of pi

    const int pi = pw[e << shift];
    const int pj = pw[(e + 1) << shift];

    const int lane = threadIdx.x & 63;
    const int prev = __shfl_up(pj, 1);

    bool is_first;
    if (k == 0)            is_first = true;                       // first step of this batch
    else if (lane == 0)    is_first = (pj != pw[(e - 1) << shift]); // cross-wave/block boundary
    else                   is_first = (pj != prev);

    if (is_first && targets[(size_t)b * NS + (size_t)pj] == 1) {
        const unsigned int bitpos = (unsigned int)b * NS + (unsigned int)pi;
        atomicOr(&mask[bitpos >> 5], 1u << (bitpos & 31));
    }
}

// ---------------------------------------------------------------------------
// Streaming loss over all B*S elements, float4-vectorized, deterministic
// per-block partial sums.
__global__ __launch_bounds__(256)
void loss_kernel(const float* __restrict__ preds, const unsigned int* __restrict__ mask,
                 float* __restrict__ partials) {
    constexpr int N4 = (NB * NS) / 4;   // 1,048,576 float4s
    float acc = 0.f;
    const int stride = gridDim.x * blockDim.x;
    for (int idx = blockIdx.x * blockDim.x + threadIdx.x; idx < N4; idx += stride) {
        const float4 x = reinterpret_cast<const float4*>(preds)[idx];
        const unsigned int m = mask[idx >> 3] >> ((idx & 7) * 4);
        const float xs[4] = {x.x, x.y, x.z, x.w};
#pragma unroll
        for (int j = 0; j < 4; ++j) {
            const float v = xs[j];
            // stable softplus: sp(v) = log1p(exp(-|v|)) + max(v,0);  sp(-v) = sp(v) - v
            const float t = log1pf(expf(-fabsf(v)));
            const float sp_pos = t + fmaxf(v, 0.f);
            const float sp_neg = sp_pos - v;
            acc += ((m >> j) & 1u) ? POS_W * sp_neg : sp_pos;
        }
    }
    // wave reduce (64 lanes)
    for (int off = 32; off; off >>= 1) acc += __shfl_down(acc, off);
    __shared__ float sacc[4];
    const int wave = threadIdx.x >> 6, lane = threadIdx.x & 63;
    if (lane == 0) sacc[wave] = acc;
    __syncthreads();
    if (threadIdx.x == 0) {
        float s = 0.f;
#pragma unroll
        for (int w = 0; w < 4; ++w) s += sacc[w];
        partials[blockIdx.x] = s;
    }
}

// ---------------------------------------------------------------------------
__global__ __launch_bounds__(256)
void final_kernel(const float* __restrict__ partials, float* __restrict__ out) {
    float acc = 0.f;
    for (int i = threadIdx.x; i < LOSS_BLOCKS; i += 256) acc += partials[i];
    for (int off = 32; off; off >>= 1) acc += __shfl_down(acc, off);
    __shared__ float sacc[4];
    const int wave = threadIdx.x >> 6, lane = threadIdx.x & 63;
    if (lane == 0) sacc[wave] = acc;
    __syncthreads();
    if (threadIdx.x == 0) {
        float s = 0.f;
#pragma unroll
        for (int w = 0; w < 4; ++w) s += sacc[w];
        out[0] = s * (1.0f / ((float)NB * (float)NS));
    }
}

// ---------------------------------------------------------------------------
extern "C" void kernel_launch(void* const* d_in, const int* in_sizes, int n_in,
                              void* d_out, int out_size, void* d_ws, size_t ws_size,
                              hipStream_t stream) {
    const float* preds   = (const float*)d_in[0];
    const int*   targets = (const int*)d_in[1];
    const int*   paths_w = (const int*)d_in[2];   // viewed as int32 words; layout auto-detected
    float*       out     = (float*)d_out;

    unsigned int* mask     = (unsigned int*)d_ws;
    int*          flag     = (int*)((char*)d_ws + (size_t)MASK_WORDS * 4);
    float*        partials = (float*)((char*)d_ws + (size_t)MASK_WORDS * 4 + 16);

    hipMemsetAsync(d_ws, 0, (size_t)MASK_WORDS * 4, stream);
    detect_kernel<<<1, 64, 0, stream>>>(paths_w, flag);

    dim3 g1(NP / 256, NB);
    gt_kernel<<<g1, 256, 0, stream>>>(paths_w, targets, mask, flag);

    loss_kernel<<<LOSS_BLOCKS, 256, 0, stream>>>(preds, mask, partials);
    final_kernel<<<1, 256, 0, stream>>>(partials, out);
}

// Round 2
// 82.135 us; speedup vs baseline: 1.3258x; 1.3258x over previous
//
#include <hip/hip_runtime.h>

// Problem constants (fixed by the reference's setup_inputs):
//   B=128 batches, S=32768 sequence, P=65536 path steps.
#define NB 128
#define NS 32768
#define NP 65536
#define POS_W 5.0f

constexpr int MASK_WORDS = (NB * NS) / 32;   // 131072 words = 512 KB bitmask
constexpr int LOSS_BLOCKS = 1024;

// ws layout:
//   [0, MASK_WORDS*4)                     : gt bitmask (zeroed each launch)
//   [MASK_WORDS*4, +4)                    : int32 layout-detect flag
//   [MASK_WORDS*4 + 16, +LOSS_BLOCKS*4)   : per-block partial sums

// ---------------------------------------------------------------------------
// Detect whether paths buffer is int32 (JAX x64 off) or int64 layout.
// Word at odd index 2P-1: int32 layout -> pj[b=0,k=P-1] (max of 65536 draws
// from [0,32768), certainly nonzero); int64 layout -> hi word of an int64 = 0.
__global__ void detect_kernel(const int* __restrict__ pw, int* __restrict__ flag) {
    if (threadIdx.x == 0 && blockIdx.x == 0) {
        flag[0] = (pw[2 * (size_t)NP - 1] != 0) ? 0 : 1;  // 0 = int32, 1 = int64
    }
}

// ---------------------------------------------------------------------------
// Two steps per thread. pi,pj are sorted per batch; is_first via run boundary.
__global__ __launch_bounds__(256)
void gt_kernel(const int* __restrict__ pw, const int* __restrict__ targets,
               unsigned int* __restrict__ mask, const int* __restrict__ flag) {
    const int shift = __builtin_amdgcn_readfirstlane(flag[0]);  // uniform branch
    const int b = blockIdx.y;
    const int k = (blockIdx.x * blockDim.x + threadIdx.x) * 2;  // steps k, k+1
    const size_t step = (size_t)b * NP + (size_t)k;

    int pi0, pj0, pi1, pj1;
    if (shift) {
        // int64 layout: one pair = int4 {pi_lo, pi_hi, pj_lo, pj_hi}
        const int4* p4 = (const int4*)pw;
        const int4 a = p4[step];
        const int4 c = p4[step + 1];
        pi0 = a.x; pj0 = a.z; pi1 = c.x; pj1 = c.z;
    } else {
        // int32 layout: two pairs = int4 {pi0, pj0, pi1, pj1}
        const int4* p4 = (const int4*)pw;
        const int4 a = p4[step >> 1];
        pi0 = a.x; pj0 = a.y; pi1 = a.z; pj1 = a.w;
    }

    const int lane = threadIdx.x & 63;
    const int prev = __shfl_up(pj1, 1);   // previous thread's last pj

    bool f0;
    if (k == 0) {
        f0 = true;
    } else if (lane == 0) {
        // pj[k-1] is element (2*step - 1); word index = elem << shift (lo word)
        const size_t w = ((size_t)(2 * step - 1)) << shift;
        f0 = (pj0 != pw[w]);
    } else {
        f0 = (pj0 != prev);
    }
    const bool f1 = (pj1 != pj0);

    const int* tg = targets + (size_t)b * NS;
    const bool h0 = f0 && (tg[pj0] == 1);
    const bool h1 = f1 && (tg[pj1] == 1);

    if (h0 | h1) {
        const unsigned base = (unsigned)b * NS;
        const unsigned bp0 = base + (unsigned)pi0;
        const unsigned bp1 = base + (unsigned)pi1;
        const unsigned w0 = bp0 >> 5, w1 = bp1 >> 5;
        const unsigned c0 = h0 ? (1u << (bp0 & 31)) : 0u;
        const unsigned c1 = h1 ? (1u << (bp1 & 31)) : 0u;
        if (h0 && h1 && w0 == w1) {
            atomicOr(&mask[w0], c0 | c1);
        } else {
            if (h0) atomicOr(&mask[w0], c0);
            if (h1) atomicOr(&mask[w1], c1);
        }
    }
}

// ---------------------------------------------------------------------------
// Streaming loss over all B*S elements, float4-vectorized, deterministic
// per-block partial sums. Native v_exp_f32/v_log_f32 via __expf/__logf.
__global__ __launch_bounds__(256)
void loss_kernel(const float* __restrict__ preds, const unsigned int* __restrict__ mask,
                 float* __restrict__ partials) {
    constexpr int N4 = (NB * NS) / 4;   // 1,048,576 float4s
    float acc = 0.f;
    const int stride = gridDim.x * blockDim.x;
    for (int idx = blockIdx.x * blockDim.x + threadIdx.x; idx < N4; idx += stride) {
        const float4 x = reinterpret_cast<const float4*>(preds)[idx];
        const unsigned int m = mask[idx >> 3] >> ((idx & 7) * 4);
        const float xs[4] = {x.x, x.y, x.z, x.w};
#pragma unroll
        for (int j = 0; j < 4; ++j) {
            const float v = xs[j];
            // stable softplus: sp(v) = log(1+exp(-|v|)) + max(v,0);  sp(-v) = sp(v) - v
            const float t = __logf(1.f + __expf(-fabsf(v)));
            const float sp_pos = t + fmaxf(v, 0.f);
            const float sp_neg = sp_pos - v;
            acc += ((m >> j) & 1u) ? POS_W * sp_neg : sp_pos;
        }
    }
    // wave reduce (64 lanes)
    for (int off = 32; off; off >>= 1) acc += __shfl_down(acc, off);
    __shared__ float sacc[4];
    const int wave = threadIdx.x >> 6, lane = threadIdx.x & 63;
    if (lane == 0) sacc[wave] = acc;
    __syncthreads();
    if (threadIdx.x == 0) {
        float s = 0.f;
#pragma unroll
        for (int w = 0; w < 4; ++w) s += sacc[w];
        partials[blockIdx.x] = s;
    }
}

// ---------------------------------------------------------------------------
__global__ __launch_bounds__(256)
void final_kernel(const float* __restrict__ partials, float* __restrict__ out) {
    float acc = 0.f;
    for (int i = threadIdx.x; i < LOSS_BLOCKS; i += 256) acc += partials[i];
    for (int off = 32; off; off >>= 1) acc += __shfl_down(acc, off);
    __shared__ float sacc[4];
    const int wave = threadIdx.x >> 6, lane = threadIdx.x & 63;
    if (lane == 0) sacc[wave] = acc;
    __syncthreads();
    if (threadIdx.x == 0) {
        float s = 0.f;
#pragma unroll
        for (int w = 0; w < 4; ++w) s += sacc[w];
        out[0] = s * (1.0f / ((float)NB * (float)NS));
    }
}

// ---------------------------------------------------------------------------
extern "C" void kernel_launch(void* const* d_in, const int* in_sizes, int n_in,
                              void* d_out, int out_size, void* d_ws, size_t ws_size,
                              hipStream_t stream) {
    const float* preds   = (const float*)d_in[0];
    const int*   targets = (const int*)d_in[1];
    const int*   paths_w = (const int*)d_in[2];   // int32 words; layout auto-detected
    float*       out     = (float*)d_out;

    unsigned int* mask     = (unsigned int*)d_ws;
    int*          flag     = (int*)((char*)d_ws + (size_t)MASK_WORDS * 4);
    float*        partials = (float*)((char*)d_ws + (size_t)MASK_WORDS * 4 + 16);

    hipMemsetAsync(d_ws, 0, (size_t)MASK_WORDS * 4, stream);
    detect_kernel<<<1, 64, 0, stream>>>(paths_w, flag);

    dim3 g1(NP / (256 * 2), NB);
    gt_kernel<<<g1, 256, 0, stream>>>(paths_w, targets, mask, flag);

    loss_kernel<<<LOSS_BLOCKS, 256, 0, stream>>>(preds, mask, partials);
    final_kernel<<<1, 256, 0, stream>>>(partials, out);
}

// Round 3
// 75.839 us; speedup vs baseline: 1.4359x; 1.0830x over previous
//
#include <hip/hip_runtime.h>

// Problem constants (fixed by the reference's setup_inputs):
//   B=128 batches, S=32768 sequence, P=65536 path steps.
#define NB 128
#define NS 32768
#define NP 65536
#define POS_W 5.0f

constexpr int MASK_WORDS = (NB * NS) / 32;   // 131072 words = 512 KB bitmask
constexpr int LOSS_BLOCKS = 1024;
constexpr int GT_BLOCKS   = 2048;            // 16 blocks per batch, 8 blocks/CU
// Each gt block covers 4096 consecutive steps of one batch (65536/4096 = 16).

// ws layout:
//   [0, MASK_WORDS*4)                     : gt bitmask (zeroed each launch)
//   [MASK_WORDS*4 + 16, +LOSS_BLOCKS*4)   : per-block partial sums

// ---------------------------------------------------------------------------
// Grid-strided gt builder. pi,pj sorted per batch; is_first via run boundary.
// Paths layout (int32 vs int64 words) detected with a uniform scalar load.
__global__ __launch_bounds__(256)
void gt_kernel(const int* __restrict__ pw, const int* __restrict__ targets,
               unsigned int* __restrict__ mask) {
    // int32 layout -> word at odd index 2P-1 is pj[b=0,k=P-1] (nonzero);
    // int64 layout -> hi word of an int64 = 0.  Uniform -> scalar branch.
    const int is64 = (pw[2 * (size_t)NP - 1] == 0);

    const int b    = blockIdx.x >> 4;            // 16 blocks per batch
    const int k0   = (blockIdx.x & 15) * 4096;   // base step within batch
    const int tid  = threadIdx.x;
    const int lane = tid & 63;
    const int* tg  = targets + (size_t)b * NS;
    const unsigned mbase = (unsigned)b * NS;
    const int4* p4 = (const int4*)pw;

    if (is64) {
        // int64 layout: one int4 = one (pi,pj) pair. Unit-stride per lane.
        #pragma unroll 2
        for (int it = 0; it < 16; ++it) {
            const int k = k0 + it * 256 + tid;
            const size_t step = (size_t)b * NP + (size_t)k;
            const int4 a = p4[step];
            const int pi = a.x, pj = a.z;
            const int prev = __shfl_up(pj, 1);
            bool f;
            if (lane == 0) {
                // pj[k-1] lo-word is at word index (2*step-1)*2
                f = (k == 0) ? true : (pj != pw[((size_t)(2 * step - 1)) << 1]);
            } else {
                f = (pj != prev);
            }
            if (f && tg[pj] == 1) {
                const unsigned bp = mbase + (unsigned)pi;
                atomicOr(&mask[bp >> 5], 1u << (bp & 31));
            }
        }
    } else {
        // int32 layout: one int4 = two pairs {pi0,pj0,pi1,pj1}.
        #pragma unroll 2
        for (int it = 0; it < 8; ++it) {
            const int k = k0 + it * 512 + tid * 2;   // steps k, k+1
            const size_t step = (size_t)b * NP + (size_t)k;
            const int4 a = p4[step >> 1];
            const int pi0 = a.x, pj0 = a.y, pi1 = a.z, pj1 = a.w;
            const int prev = __shfl_up(pj1, 1);
            bool f0;
            if (lane == 0) {
                f0 = (k == 0) ? true : (pj0 != pw[2 * step - 1]);
            } else {
                f0 = (pj0 != prev);
            }
            const bool f1 = (pj1 != pj0);
            const bool h0 = f0 && (tg[pj0] == 1);
            const bool h1 = f1 && (tg[pj1] == 1);
            if (h0 | h1) {
                const unsigned bp0 = mbase + (unsigned)pi0;
                const unsigned bp1 = mbase + (unsigned)pi1;
                const unsigned w0 = bp0 >> 5, w1 = bp1 >> 5;
                const unsigned c0 = h0 ? (1u << (bp0 & 31)) : 0u;
                const unsigned c1 = h1 ? (1u << (bp1 & 31)) : 0u;
                if (h0 && h1 && w0 == w1) {
                    atomicOr(&mask[w0], c0 | c1);
                } else {
                    if (h0) atomicOr(&mask[w0], c0);
                    if (h1) atomicOr(&mask[w1], c1);
                }
            }
        }
    }
}

// ---------------------------------------------------------------------------
// Streaming loss over all B*S elements, float4-vectorized, deterministic
// per-block partial sums. Native v_exp_f32/v_log_f32 via __expf/__logf.
__global__ __launch_bounds__(256)
void loss_kernel(const float* __restrict__ preds, const unsigned int* __restrict__ mask,
                 float* __restrict__ partials) {
    constexpr int N4 = (NB * NS) / 4;   // 1,048,576 float4s
    float acc = 0.f;
    const int stride = gridDim.x * blockDim.x;
    for (int idx = blockIdx.x * blockDim.x + threadIdx.x; idx < N4; idx += stride) {
        const float4 x = reinterpret_cast<const float4*>(preds)[idx];
        const unsigned int m = mask[idx >> 3] >> ((idx & 7) * 4);
        const float xs[4] = {x.x, x.y, x.z, x.w};
#pragma unroll
        for (int j = 0; j < 4; ++j) {
            const float v = xs[j];
            // stable softplus: sp(v) = log(1+exp(-|v|)) + max(v,0);  sp(-v) = sp(v) - v
            const float t = __logf(1.f + __expf(-fabsf(v)));
            const float sp_pos = t + fmaxf(v, 0.f);
            const float sp_neg = sp_pos - v;
            acc += ((m >> j) & 1u) ? POS_W * sp_neg : sp_pos;
        }
    }
    // wave reduce (64 lanes)
    for (int off = 32; off; off >>= 1) acc += __shfl_down(acc, off);
    __shared__ float sacc[4];
    const int wave = threadIdx.x >> 6, lane = threadIdx.x & 63;
    if (lane == 0) sacc[wave] = acc;
    __syncthreads();
    if (threadIdx.x == 0) {
        float s = 0.f;
#pragma unroll
        for (int w = 0; w < 4; ++w) s += sacc[w];
        partials[blockIdx.x] = s;
    }
}

// ---------------------------------------------------------------------------
__global__ __launch_bounds__(256)
void final_kernel(const float* __restrict__ partials, float* __restrict__ out) {
    float acc = 0.f;
    for (int i = threadIdx.x; i < LOSS_BLOCKS; i += 256) acc += partials[i];
    for (int off = 32; off; off >>= 1) acc += __shfl_down(acc, off);
    __shared__ float sacc[4];
    const int wave = threadIdx.x >> 6, lane = threadIdx.x & 63;
    if (lane == 0) sacc[wave] = acc;
    __syncthreads();
    if (threadIdx.x == 0) {
        float s = 0.f;
#pragma unroll
        for (int w = 0; w < 4; ++w) s += sacc[w];
        out[0] = s * (1.0f / ((float)NB * (float)NS));
    }
}

// ---------------------------------------------------------------------------
extern "C" void kernel_launch(void* const* d_in, const int* in_sizes, int n_in,
                              void* d_out, int out_size, void* d_ws, size_t ws_size,
                              hipStream_t stream) {
    const float* preds   = (const float*)d_in[0];
    const int*   targets = (const int*)d_in[1];
    const int*   paths_w = (const int*)d_in[2];   // int32 words; layout auto-detected
    float*       out     = (float*)d_out;

    unsigned int* mask     = (unsigned int*)d_ws;
    float*        partials = (float*)((char*)d_ws + (size_t)MASK_WORDS * 4 + 16);

    hipMemsetAsync(d_ws, 0, (size_t)MASK_WORDS * 4, stream);

    gt_kernel<<<GT_BLOCKS, 256, 0, stream>>>(paths_w, targets, mask);

    loss_kernel<<<LOSS_BLOCKS, 256, 0, stream>>>(preds, mask, partials);
    final_kernel<<<1, 256, 0, stream>>>(partials, out);
}

// Round 4
// 37.902 us; speedup vs baseline: 2.8731x; 2.0009x over previous
//
#include <hip/hip_runtime.h>

// Problem constants (fixed by the reference's setup_inputs):
//   B=128 batches, S=32768 sequence, P=65536 path steps.
#define NB 128
#define NS 32768
#define NP 65536
#define POS_W 5.0f

constexpr int MASK_WORDS = (NB * NS) / 32;   // 131072 words = 512 KB per mask plane
constexpr int WPB        = NS / 32;          // 1024 mask words per batch (4 KB)
constexpr int LOSS_BLOCKS = 1024;

// ws layout:
//   [0, QPB*MASK_WORDS*4)  : QPB partial gt-mask planes (fully written by gt_kernel)
//   [+0, LOSS_BLOCKS*4)    : per-block loss partials (after the planes)

// ---------------------------------------------------------------------------
// One block = (batch b, quarter q). All random accesses stay in LDS:
//   - targets staged as a 4 KB bitmap via ballot (coalesced global reads)
//   - gt bits built with LDS atomics (ds_or), zero fabric atomics
// Partial plane written with plain coalesced stores; loss kernel ORs planes.
template <int QPB>
__global__ __launch_bounds__(1024)
void gt_kernel(const int* __restrict__ pw, const int* __restrict__ targets,
               unsigned int* __restrict__ pmask) {
    __shared__ unsigned int tbits[WPB];   // 4 KB: targets[b] as bits
    __shared__ unsigned int gbits[WPB];   // 4 KB: gt bits for batch b (this block's part)

    // Layout detect (uniform scalar): int64 -> hi word of last elem == 0.
    const int is64 = (pw[2 * (size_t)NP - 1] == 0);

    const int q   = blockIdx.x;           // quarter within batch
    const int b   = blockIdx.y;           // batch
    const int tid = threadIdx.x;          // 0..1023
    const int lane = tid & 63;
    const int wave = tid >> 6;            // 0..15

    // ---- stage targets as bits (ballot over 64 consecutive values) ----
    const int* tg = targets + (size_t)b * NS;
    for (int seg = wave; seg < NS / 64; seg += 16) {
        const int v = tg[seg * 64 + lane];
        const unsigned long long m = __ballot(v == 1);
        if (lane == 0)  tbits[seg * 2]     = (unsigned int)m;
        if (lane == 32) tbits[seg * 2 + 1] = (unsigned int)(m >> 32);
    }
    gbits[tid] = 0u;
    __syncthreads();

    // ---- stream this block's path steps ----
    constexpr int STEPS = NP / QPB;       // steps per block
    const int k0 = q * STEPS;
    const int4* p4 = (const int4*)pw;

    if (is64) {
        // int64 layout: one int4 = one (pi,pj) pair, unit-stride per lane.
        #pragma unroll 2
        for (int it = 0; it < STEPS / 1024; ++it) {
            const int k = k0 + it * 1024 + tid;
            const size_t step = (size_t)b * NP + (size_t)k;
            const int4 a = p4[step];
            const int pi = a.x, pj = a.z;
            const int prev = __shfl_up(pj, 1);
            bool f;
            if (lane == 0) {
                f = (k == 0) ? true : (pj != pw[((size_t)(2 * step - 1)) << 1]);
            } else {
                f = (pj != prev);
            }
            if (f && ((tbits[pj >> 5] >> (pj & 31)) & 1u)) {
                atomicOr(&gbits[pi >> 5], 1u << (pi & 31));
            }
        }
    } else {
        // int32 layout: one int4 = two pairs {pi0,pj0,pi1,pj1}.
        #pragma unroll 2
        for (int it = 0; it < STEPS / 2048; ++it) {
            const int k = k0 + (it * 1024 + tid) * 2;
            const size_t step = (size_t)b * NP + (size_t)k;
            const int4 a = p4[step >> 1];
            const int pi0 = a.x, pj0 = a.y, pi1 = a.z, pj1 = a.w;
            const int prev = __shfl_up(pj1, 1);
            bool f0;
            if (lane == 0) {
                f0 = (k == 0) ? true : (pj0 != pw[2 * step - 1]);
            } else {
                f0 = (pj0 != prev);
            }
            const bool f1 = (pj1 != pj0);
            if (f0 && ((tbits[pj0 >> 5] >> (pj0 & 31)) & 1u))
                atomicOr(&gbits[pi0 >> 5], 1u << (pi0 & 31));
            if (f1 && ((tbits[pj1 >> 5] >> (pj1 & 31)) & 1u))
                atomicOr(&gbits[pi1 >> 5], 1u << (pi1 & 31));
        }
    }
    __syncthreads();

    // ---- write this block's partial plane (plain coalesced stores) ----
    pmask[(size_t)q * MASK_WORDS + (size_t)b * WPB + tid] = gbits[tid];
}

// ---------------------------------------------------------------------------
// Streaming loss, float4-vectorized; gt bit = OR of QPB partial planes.
__global__ __launch_bounds__(256)
void loss_kernel(const float* __restrict__ preds, const unsigned int* __restrict__ pmask,
                 float* __restrict__ partials, int qpb) {
    constexpr int N4 = (NB * NS) / 4;   // 1,048,576 float4s
    float acc = 0.f;
    const int stride = gridDim.x * blockDim.x;
    for (int idx = blockIdx.x * blockDim.x + threadIdx.x; idx < N4; idx += stride) {
        const float4 x = reinterpret_cast<const float4*>(preds)[idx];
        unsigned int mw = 0u;
        for (int q = 0; q < qpb; ++q)
            mw |= pmask[(size_t)q * MASK_WORDS + (idx >> 3)];
        const unsigned int m = mw >> ((idx & 7) * 4);
        const float xs[4] = {x.x, x.y, x.z, x.w};
#pragma unroll
        for (int j = 0; j < 4; ++j) {
            const float v = xs[j];
            // stable softplus: sp(v) = log(1+exp(-|v|)) + max(v,0);  sp(-v) = sp(v) - v
            const float t = __logf(1.f + __expf(-fabsf(v)));
            const float sp_pos = t + fmaxf(v, 0.f);
            const float sp_neg = sp_pos - v;
            acc += ((m >> j) & 1u) ? POS_W * sp_neg : sp_pos;
        }
    }
    for (int off = 32; off; off >>= 1) acc += __shfl_down(acc, off);
    __shared__ float sacc[4];
    const int wave = threadIdx.x >> 6, lane = threadIdx.x & 63;
    if (lane == 0) sacc[wave] = acc;
    __syncthreads();
    if (threadIdx.x == 0) {
        float s = 0.f;
#pragma unroll
        for (int w = 0; w < 4; ++w) s += sacc[w];
        partials[blockIdx.x] = s;
    }
}

// ---------------------------------------------------------------------------
__global__ __launch_bounds__(256)
void final_kernel(const float* __restrict__ partials, float* __restrict__ out) {
    float acc = 0.f;
    for (int i = threadIdx.x; i < LOSS_BLOCKS; i += 256) acc += partials[i];
    for (int off = 32; off; off >>= 1) acc += __shfl_down(acc, off);
    __shared__ float sacc[4];
    const int wave = threadIdx.x >> 6, lane = threadIdx.x & 63;
    if (lane == 0) sacc[wave] = acc;
    __syncthreads();
    if (threadIdx.x == 0) {
        float s = 0.f;
#pragma unroll
        for (int w = 0; w < 4; ++w) s += sacc[w];
        out[0] = s * (1.0f / ((float)NB * (float)NS));
    }
}

// ---------------------------------------------------------------------------
extern "C" void kernel_launch(void* const* d_in, const int* in_sizes, int n_in,
                              void* d_out, int out_size, void* d_ws, size_t ws_size,
                              hipStream_t stream) {
    const float* preds   = (const float*)d_in[0];
    const int*   targets = (const int*)d_in[1];
    const int*   paths_w = (const int*)d_in[2];   // int32 words; layout auto-detected
    float*       out     = (float*)d_out;

    // Pick planes-per-batch by available workspace (deterministic for fixed ws).
    int qpb = 4;
    while (qpb > 1 &&
           ws_size < (size_t)qpb * MASK_WORDS * 4 + (size_t)LOSS_BLOCKS * 4)
        qpb >>= 1;

    unsigned int* pmask    = (unsigned int*)d_ws;
    float*        partials = (float*)((char*)d_ws + (size_t)qpb * MASK_WORDS * 4);

    dim3 g1(qpb, NB);
    switch (qpb) {
        case 4: gt_kernel<4><<<g1, 1024, 0, stream>>>(paths_w, targets, pmask); break;
        case 2: gt_kernel<2><<<g1, 1024, 0, stream>>>(paths_w, targets, pmask); break;
        default: gt_kernel<1><<<g1, 1024, 0, stream>>>(paths_w, targets, pmask); break;
    }

    loss_kernel<<<LOSS_BLOCKS, 256, 0, stream>>>(preds, pmask, partials, qpb);
    final_kernel<<<1, 256, 0, stream>>>(partials, out);
}

// Round 5
// 34.085 us; speedup vs baseline: 3.1948x; 1.1120x over previous
//
#include <hip/hip_runtime.h>

// Problem constants (fixed by the reference's setup_inputs):
//   B=128 batches, S=32768 sequence, P=65536 path steps.
#define NB 128
#define NS 32768
#define NP 65536
#define POS_W 5.0f

constexpr int MASK_WORDS = (NB * NS) / 32;   // 131072 words = 512 KB per mask plane
constexpr int WPB        = NS / 32;          // 1024 mask words per batch (4 KB)
constexpr int LOSS_BLOCKS = 1024;

// ws layout:
//   [0, MASK_WORDS*4)                         : global targets bitmap (tbits)
//   [MASK_WORDS*4, +QPB*MASK_WORDS*4)         : QPB partial gt-mask planes
//   [after planes]                            : per-block loss partials

// ---------------------------------------------------------------------------
// One-shot: targets (16 MB int32) -> 512 KB bitmap, via per-wave ballot.
__global__ __launch_bounds__(256)
void tbit_kernel(const int* __restrict__ targets, unsigned int* __restrict__ tb) {
    constexpr int NSEG = NB * NS / 64;
    const int lane = threadIdx.x & 63;
    const int wid  = (blockIdx.x * blockDim.x + threadIdx.x) >> 6;
    const int nw   = (gridDim.x * blockDim.x) >> 6;
    for (int s = wid; s < NSEG; s += nw) {
        const unsigned long long m = __ballot(targets[(size_t)s * 64 + lane] != 0);
        if (lane == 0)       tb[s * 2]     = (unsigned int)m;
        else if (lane == 32) tb[s * 2 + 1] = (unsigned int)(m >> 32);
    }
}

// ---------------------------------------------------------------------------
// One block = (batch b, quarter q). Random accesses stay in LDS:
//   - targets bitmap: one coalesced 4 KB load from the precomputed global bitmap
//   - gt bits built with LDS atomics (ds_or), zero fabric atomics
// Partial plane written with plain coalesced stores; loss kernel ORs planes.
template <int QPB>
__global__ __launch_bounds__(1024)
void gt_kernel(const int* __restrict__ pw, const unsigned int* __restrict__ tbits_g,
               unsigned int* __restrict__ pmask) {
    __shared__ unsigned int tbits[WPB];   // 4 KB: targets[b] as bits
    __shared__ unsigned int gbits[WPB];   // 4 KB: gt bits for batch b (this block's part)

    // Layout detect (uniform scalar): int64 -> hi word of last elem == 0.
    const int is64 = (pw[2 * (size_t)NP - 1] == 0);

    const int q   = blockIdx.x;           // quarter within batch
    const int b   = blockIdx.y;           // batch
    const int tid = threadIdx.x;          // 0..1023
    const int lane = tid & 63;

    tbits[tid] = tbits_g[(size_t)b * WPB + tid];   // 4 KB coalesced
    gbits[tid] = 0u;
    __syncthreads();

    constexpr int STEPS = NP / QPB;       // steps per block
    const int k0 = q * STEPS;
    const int4* p4 = (const int4*)pw;

    if (is64) {
        // int64 layout: one int4 = one (pi,pj) pair, unit-stride per lane.
        #pragma unroll 4
        for (int it = 0; it < STEPS / 1024; ++it) {
            const int k = k0 + it * 1024 + tid;
            const size_t step = (size_t)b * NP + (size_t)k;
            const int4 a = p4[step];
            const int pi = a.x, pj = a.z;
            const int prev = __shfl_up(pj, 1);
            bool f;
            if (lane == 0) {
                f = (k == 0) ? true : (pj != pw[((size_t)(2 * step - 1)) << 1]);
            } else {
                f = (pj != prev);
            }
            if (f && ((tbits[pj >> 5] >> (pj & 31)) & 1u)) {
                atomicOr(&gbits[pi >> 5], 1u << (pi & 31));
            }
        }
    } else {
        // int32 layout: one int4 = two pairs {pi0,pj0,pi1,pj1}.
        #pragma unroll 4
        for (int it = 0; it < STEPS / 2048; ++it) {
            const int k = k0 + (it * 1024 + tid) * 2;
            const size_t step = (size_t)b * NP + (size_t)k;
            const int4 a = p4[step >> 1];
            const int pi0 = a.x, pj0 = a.y, pi1 = a.z, pj1 = a.w;
            const int prev = __shfl_up(pj1, 1);
            bool f0;
            if (lane == 0) {
                f0 = (k == 0) ? true : (pj0 != pw[2 * step - 1]);
            } else {
                f0 = (pj0 != prev);
            }
            const bool f1 = (pj1 != pj0);
            if (f0 && ((tbits[pj0 >> 5] >> (pj0 & 31)) & 1u))
                atomicOr(&gbits[pi0 >> 5], 1u << (pi0 & 31));
            if (f1 && ((tbits[pj1 >> 5] >> (pj1 & 31)) & 1u))
                atomicOr(&gbits[pi1 >> 5], 1u << (pi1 & 31));
        }
    }
    __syncthreads();

    // ---- write this block's partial plane (plain coalesced stores) ----
    pmask[(size_t)q * MASK_WORDS + (size_t)b * WPB + tid] = gbits[tid];
}

// ---------------------------------------------------------------------------
// Streaming loss, float4-vectorized; gt bit = OR of QPB partial planes.
__global__ __launch_bounds__(256)
void loss_kernel(const float* __restrict__ preds, const unsigned int* __restrict__ pmask,
                 float* __restrict__ partials, int qpb) {
    constexpr int N4 = (NB * NS) / 4;   // 1,048,576 float4s
    float acc = 0.f;
    const int stride = gridDim.x * blockDim.x;
    for (int idx = blockIdx.x * blockDim.x + threadIdx.x; idx < N4; idx += stride) {
        const float4 x = reinterpret_cast<const float4*>(preds)[idx];
        unsigned int mw = 0u;
        for (int q = 0; q < qpb; ++q)
            mw |= pmask[(size_t)q * MASK_WORDS + (idx >> 3)];
        const unsigned int m = mw >> ((idx & 7) * 4);
        const float xs[4] = {x.x, x.y, x.z, x.w};
#pragma unroll
        for (int j = 0; j < 4; ++j) {
            const float v = xs[j];
            // stable softplus: sp(v) = log(1+exp(-|v|)) + max(v,0);  sp(-v) = sp(v) - v
            const float t = __logf(1.f + __expf(-fabsf(v)));
            const float sp_pos = t + fmaxf(v, 0.f);
            const float sp_neg = sp_pos - v;
            acc += ((m >> j) & 1u) ? POS_W * sp_neg : sp_pos;
        }
    }
    for (int off = 32; off; off >>= 1) acc += __shfl_down(acc, off);
    __shared__ float sacc[4];
    const int wave = threadIdx.x >> 6, lane = threadIdx.x & 63;
    if (lane == 0) sacc[wave] = acc;
    __syncthreads();
    if (threadIdx.x == 0) {
        float s = 0.f;
#pragma unroll
        for (int w = 0; w < 4; ++w) s += sacc[w];
        partials[blockIdx.x] = s;
    }
}

// ---------------------------------------------------------------------------
__global__ __launch_bounds__(256)
void final_kernel(const float* __restrict__ partials, float* __restrict__ out) {
    float acc = 0.f;
    for (int i = threadIdx.x; i < LOSS_BLOCKS; i += 256) acc += partials[i];
    for (int off = 32; off; off >>= 1) acc += __shfl_down(acc, off);
    __shared__ float sacc[4];
    const int wave = threadIdx.x >> 6, lane = threadIdx.x & 63;
    if (lane == 0) sacc[wave] = acc;
    __syncthreads();
    if (threadIdx.x == 0) {
        float s = 0.f;
#pragma unroll
        for (int w = 0; w < 4; ++w) s += sacc[w];
        out[0] = s * (1.0f / ((float)NB * (float)NS));
    }
}

// ---------------------------------------------------------------------------
extern "C" void kernel_launch(void* const* d_in, const int* in_sizes, int n_in,
                              void* d_out, int out_size, void* d_ws, size_t ws_size,
                              hipStream_t stream) {
    const float* preds   = (const float*)d_in[0];
    const int*   targets = (const int*)d_in[1];
    const int*   paths_w = (const int*)d_in[2];   // int32 words; layout auto-detected
    float*       out     = (float*)d_out;

    // Pick planes-per-batch by available workspace (deterministic for fixed ws).
    int qpb = 4;
    while (qpb > 1 &&
           ws_size < (size_t)(1 + qpb) * MASK_WORDS * 4 + (size_t)LOSS_BLOCKS * 4)
        qpb >>= 1;

    unsigned int* tbits_g  = (unsigned int*)d_ws;
    unsigned int* pmask    = tbits_g + MASK_WORDS;
    float*        partials = (float*)((char*)d_ws +
                              (size_t)(1 + qpb) * MASK_WORDS * 4);

    tbit_kernel<<<1024, 256, 0, stream>>>(targets, tbits_g);

    dim3 g1(qpb, NB);
    switch (qpb) {
        case 4: gt_kernel<4><<<g1, 1024, 0, stream>>>(paths_w, tbits_g, pmask); break;
        case 2: gt_kernel<2><<<g1, 1024, 0, stream>>>(paths_w, tbits_g, pmask); break;
        default: gt_kernel<1><<<g1, 1024, 0, stream>>>(paths_w, tbits_g, pmask); break;
    }

    loss_kernel<<<LOSS_BLOCKS, 256, 0, stream>>>(preds, pmask, partials, qpb);
    final_kernel<<<1, 256, 0, stream>>>(partials, out);
}